// Round 3
// baseline (915.598 us; speedup 1.0000x reference)
//
#include <hip/hip_runtime.h>
#include <hip/hip_bf16.h>
#include <stdint.h>

#define T_TOK 16384
#define HD    1024
#define HD2   2048
#define NE    8
#define ROWS  (2*T_TOK)   // 32768 expert-row assignments (exactly 2 per token)
#define MAXT  264         // max M-tiles: 32768/128 + 8 (multiple of 8 for swizzle)
#define RTOK  32          // tokens per router block

// meta layout (ints): cnt[e] at meta[e*32] (padded to cache lines, e<8)
//   nt at meta[256]; offs[8] at meta+272; tile_e/tile_r0/tile_re at meta+288 (+MAXT,+2*MAXT)
#define M_NT    256
#define M_OFFS  272
#define M_TILES 288

typedef __bf16 bf16x8 __attribute__((ext_vector_type(8)));
typedef float f32x4 __attribute__((ext_vector_type(4)));

// async 16B global->LDS (dest = wave-uniform base + lane*16)
#define GLD16(g, l) __builtin_amdgcn_global_load_lds( \
    (const __attribute__((address_space(1))) void*)(g), \
    (__attribute__((address_space(3))) void*)(l), 16, 0, 0)

__device__ inline unsigned short f2bf(float f) {  // RNE fp32->bf16
    unsigned int u = __float_as_uint(f);
    unsigned int r = (u + 0x7fffu + ((u >> 16) & 1u)) >> 16;
    return (unsigned short)r;
}

// ------------- fp32 [E][K][N] -> bf16 [E][N][K] transpose-convert -------------
__global__ __launch_bounds__(256) void cvt_wT(const float* __restrict__ w,
                                              unsigned short* __restrict__ wt,
                                              int K, int N) {
    __shared__ float t[32][33];
    int e = blockIdx.z;
    int n0 = blockIdx.x * 32, k0 = blockIdx.y * 32;
    int r = threadIdx.x >> 3;          // 0..31
    int c4 = (threadIdx.x & 7) * 4;    // 0..28
    const float* src = w + ((size_t)e * K + k0 + r) * N + n0 + c4;
    float4 v = *(const float4*)src;
    t[r][c4] = v.x; t[r][c4+1] = v.y; t[r][c4+2] = v.z; t[r][c4+3] = v.w;
    __syncthreads();
    int cc = threadIdx.x & 7;
    ushort4 o;
    o.x = f2bf(t[cc*4+0][r]); o.y = f2bf(t[cc*4+1][r]);
    o.z = f2bf(t[cc*4+2][r]); o.w = f2bf(t[cc*4+3][r]);
    *(ushort4*)(wt + ((size_t)e * N + n0 + r) * K + k0 + cc*4) = o;
}

// ------- router: fp32 logits, top-2, block-aggregated counting, fused x->bf16 -------
__global__ __launch_bounds__(256) void router_k(const float* __restrict__ x,
        const float* __restrict__ gw, int* __restrict__ meta,
        int* __restrict__ tok_e, int* __restrict__ tok_slot, float* __restrict__ tok_w,
        unsigned short* __restrict__ xb) {
    __shared__ float g[NE * HD];                 // transposed [e][k], 32 KB
    __shared__ int   le[RTOK * 2];
    __shared__ float lw[RTOK * 2];
    __shared__ int   lslot[RTOK * 2];
    __shared__ int   lcnt[NE];
    __shared__ int   lbase[NE];
    for (int i = threadIdx.x; i < NE * HD; i += 256) {
        int k = i >> 3, e = i & 7;
        g[e * HD + k] = gw[i];
    }
    if (threadIdx.x < NE) lcnt[threadIdx.x] = 0;
    __syncthreads();

    int wave = threadIdx.x >> 6, lane = threadIdx.x & 63;
    int t0 = blockIdx.x * RTOK;
    for (int i = 0; i < RTOK / 4; i++) {         // each wave: 8 tokens
        int tt = wave * (RTOK / 4) + i;
        int t = t0 + tt;
        const float4* xr = (const float4*)(x + (size_t)t * HD);
        float acc[NE];
#pragma unroll
        for (int e = 0; e < NE; e++) acc[e] = 0.f;
#pragma unroll
        for (int j = 0; j < HD / 256; j++) {     // 4 iters of float4
            float4 xv = xr[lane + 64 * j];
            ushort4 o4;
            o4.x = f2bf(xv.x); o4.y = f2bf(xv.y);
            o4.z = f2bf(xv.z); o4.w = f2bf(xv.w);
            *(ushort4*)(xb + (size_t)t * HD + (lane + 64 * j) * 4) = o4;
#pragma unroll
            for (int e = 0; e < NE; e++) {
                float4 gv = *(const float4*)&g[e * HD + (lane + 64 * j) * 4];
                acc[e] += xv.x * gv.x + xv.y * gv.y + xv.z * gv.z + xv.w * gv.w;
            }
        }
#pragma unroll
        for (int e = 0; e < NE; e++) {
            float v = acc[e];
#pragma unroll
            for (int off = 32; off > 0; off >>= 1) v += __shfl_down(v, off, 64);
            acc[e] = v;
        }
        if (lane == 0) {
            int e1 = 0; float l1 = acc[0];
#pragma unroll
            for (int e = 1; e < NE; e++) if (acc[e] > l1) { l1 = acc[e]; e1 = e; }
            int e2 = -1; float l2 = -3.0e38f;
#pragma unroll
            for (int e = 0; e < NE; e++) if (e != e1 && acc[e] > l2) { l2 = acc[e]; e2 = e; }
            float w1 = 1.f / (1.f + expf(l2 - l1));   // softmax denom cancels in top-2 renorm
            le[tt * 2] = e1;     le[tt * 2 + 1] = e2;
            lw[tt * 2] = w1;     lw[tt * 2 + 1] = 1.f - w1;
        }
    }
    __syncthreads();
    // block-local slot assignment (LDS atomics, 8 addresses)
    if (threadIdx.x < RTOK * 2)
        lslot[threadIdx.x] = atomicAdd(&lcnt[le[threadIdx.x]], 1);
    __syncthreads();
    // one global atomic per expert per block, counters padded to cache lines
    if (threadIdx.x < NE)
        lbase[threadIdx.x] = atomicAdd(&meta[threadIdx.x * 32], lcnt[threadIdx.x]);
    __syncthreads();
    if (threadIdx.x < RTOK * 2) {
        int gi = t0 * 2 + threadIdx.x;           // global row index = token*2 + k
        int e = le[threadIdx.x];
        tok_e[gi]    = e;
        tok_slot[gi] = lbase[e] + lslot[threadIdx.x];
        tok_w[gi]    = lw[threadIdx.x];
    }
}

// ------------- offsets + M-tile table (one wave, parallel fill) -------------
__global__ __launch_bounds__(64) void offsets_k(int* __restrict__ meta) {
    int lane = threadIdx.x;
    int cl = (lane < NE) ? meta[lane * 32] : 0;
    int cnt[NE], offs[NE], tbase[NE];
    int o = 0, tb = 0;
#pragma unroll
    for (int e = 0; e < NE; e++) {
        cnt[e] = __shfl(cl, e, 64);
        offs[e] = o;  o += cnt[e];
        tbase[e] = tb; tb += (cnt[e] + 127) >> 7;
    }
    int nt = tb;
    if (lane == 0) meta[M_NT] = nt;
    if (lane < NE) meta[M_OFFS + lane] = offs[lane];
    for (int i = lane; i < nt; i += 64) {
        int e = 0;
#pragma unroll
        for (int k = 1; k < NE; k++) if (i >= tbase[k]) e = k;
        int m = i - tbase[e];
        int r0 = offs[e] + m * 128;
        int re = offs[e] + cnt[e];
        if (r0 + 128 < re) re = r0 + 128;
        meta[M_TILES + i] = e;
        meta[M_TILES + MAXT + i] = r0;
        meta[M_TILES + 2 * MAXT + i] = re;
    }
}

// ------------- scatter token ids/weights into compact row space -------------
__global__ __launch_bounds__(256) void scatter_k(const int* __restrict__ meta,
        const int* __restrict__ tok_e, const int* __restrict__ tok_slot,
        const float* __restrict__ tok_w, int* __restrict__ rows_tok,
        float* __restrict__ rows_w) {
    int i = blockIdx.x * 256 + threadIdx.x;     // 0..ROWS-1
    const int* offs = meta + M_OFFS;
    int e = tok_e[i];
    int r = offs[e] + tok_slot[i];
    rows_tok[r] = i >> 1;
    rows_w[r] = tok_w[i];
}

// XCD-aware remap: the 8 n-blocks sharing one A-tile get lins {r,r+8,..} -> same XCD L2
__device__ inline void swizzle_mn(int& mt, int& n0) {
    int lin = blockIdx.y * gridDim.x + blockIdx.x;
    int xcd = lin & 7;
    int idx = lin >> 3;
    int gx = gridDim.x;                 // 8 or 16 (power of 2)
    int n_idx = idx & (gx - 1);
    int mgrp = idx / gx;
    mt = mgrp * 8 + xcd;
    n0 = n_idx * 128;
}

// ---------------- GEMM1: hdn = relu(gather(X) @ W1 + b1), bf16 out ----------------
__global__ __launch_bounds__(256) void gemm1_k(
    const unsigned short* __restrict__ Xbf,   // [T][HD]
    const unsigned short* __restrict__ W1T,   // [E][HD2][HD] (n-major, k-contig)
    const float* __restrict__ b1,             // [E][HD2]
    const int* __restrict__ meta,
    const int* __restrict__ rows_tok,
    unsigned short* __restrict__ hdn)         // [ROWS][HD2]
{
    __shared__ unsigned short As[128 * 64];
    __shared__ unsigned short Bs[128 * 64];
    int mt, n0;
    swizzle_mn(mt, n0);
    int nt = meta[M_NT];
    if (mt >= nt) return;
    int e    = meta[M_TILES + mt];
    int r0   = meta[M_TILES + MAXT + mt];
    int rend = meta[M_TILES + 2 * MAXT + mt];

    int tid = threadIdx.x, w = tid >> 6, lane = tid & 63;

    // staging: granule g = w*256 + j*64 + lane holds tile(row=g>>3, c=(g&7)^(row&7))
    const unsigned short* srcA[4];
    const unsigned short* srcB[4];
#pragma unroll
    for (int j = 0; j < 4; j++) {
        int g = w * 256 + j * 64 + lane;
        int row = g >> 3;
        int c = (g & 7) ^ (row & 7);
        int grow = r0 + row; grow = grow < ROWS - 1 ? grow : ROWS - 1;
        int tok = rows_tok[grow];
        srcA[j] = Xbf + (size_t)tok * HD + c * 8;
        srcB[j] = W1T + ((size_t)e * HD2 + n0 + row) * HD + c * 8;
    }
    int wm = (w & 1) * 64, wn = (w >> 1) * 64;

    f32x4 acc[4][4];
#pragma unroll
    for (int a = 0; a < 4; a++)
#pragma unroll
        for (int b = 0; b < 4; b++) acc[a][b] = (f32x4){0.f, 0.f, 0.f, 0.f};

    for (int kt = 0; kt < HD / 64; kt++) {
        __syncthreads();
#pragma unroll
        for (int j = 0; j < 4; j++) {
            GLD16(srcA[j] + kt * 64, &As[(w * 256 + j * 64) * 8]);
            GLD16(srcB[j] + kt * 64, &Bs[(w * 256 + j * 64) * 8]);
        }
        __syncthreads();
#pragma unroll
        for (int s = 0; s < 2; s++) {
            bf16x8 af[4], bfr[4];
            int q = lane >> 4, cA = s * 4 + q;
#pragma unroll
            for (int i = 0; i < 4; i++) {
                int rowA = wm + i * 16 + (lane & 15);
                af[i] = *(const bf16x8*)&As[(rowA * 8 + (cA ^ (rowA & 7))) * 8];
                int rowB = wn + i * 16 + (lane & 15);
                bfr[i] = *(const bf16x8*)&Bs[(rowB * 8 + (cA ^ (rowB & 7))) * 8];
            }
#pragma unroll
            for (int im = 0; im < 4; im++)
#pragma unroll
                for (int in = 0; in < 4; in++)
                    acc[im][in] = __builtin_amdgcn_mfma_f32_16x16x32_bf16(
                        af[im], bfr[in], acc[im][in], 0, 0, 0);
        }
    }

    const float* b1e = b1 + (size_t)e * HD2 + n0 + wn;
    int q = lane >> 4;
#pragma unroll
    for (int in = 0; in < 4; in++) {
        float bias = b1e[in * 16 + (lane & 15)];
#pragma unroll
        for (int im = 0; im < 4; im++) {
            int rbase = r0 + wm + im * 16 + q * 4;
#pragma unroll
            for (int i = 0; i < 4; i++) {
                int r = rbase + i;
                if (r < rend) {
                    float v = acc[im][in][i] + bias;
                    v = v > 0.f ? v : 0.f;
                    hdn[(size_t)r * HD2 + n0 + wn + in * 16 + (lane & 15)] = f2bf(v);
                }
            }
        }
    }
}

// ---------------- GEMM2: out[tok] += w * (hdn @ W2 + b2), fp32 atomics ----------------
__global__ __launch_bounds__(256) void gemm2_k(
    const unsigned short* __restrict__ hdn,   // [ROWS][HD2]
    const unsigned short* __restrict__ W2T,   // [E][HD][HD2]
    const float* __restrict__ b2,             // [E][HD]
    const int* __restrict__ meta,
    const int* __restrict__ rows_tok,
    const float* __restrict__ rows_w,
    float* __restrict__ out)                  // [T][HD]
{
    __shared__ unsigned short As[128 * 64];
    __shared__ unsigned short Bs[128 * 64];
    int mt, n0;
    swizzle_mn(mt, n0);
    int nt = meta[M_NT];
    if (mt >= nt) return;
    int e    = meta[M_TILES + mt];
    int r0   = meta[M_TILES + MAXT + mt];
    int rend = meta[M_TILES + 2 * MAXT + mt];

    int tid = threadIdx.x, w = tid >> 6, lane = tid & 63;

    const unsigned short* srcA[4];
    const unsigned short* srcB[4];
#pragma unroll
    for (int j = 0; j < 4; j++) {
        int g = w * 256 + j * 64 + lane;
        int row = g >> 3;
        int c = (g & 7) ^ (row & 7);
        int grow = r0 + row; grow = grow < ROWS - 1 ? grow : ROWS - 1;
        srcA[j] = hdn + (size_t)grow * HD2 + c * 8;
        srcB[j] = W2T + ((size_t)e * HD + n0 + row) * HD2 + c * 8;
    }
    int wm = (w & 1) * 64, wn = (w >> 1) * 64;

    f32x4 acc[4][4];
#pragma unroll
    for (int a = 0; a < 4; a++)
#pragma unroll
        for (int b = 0; b < 4; b++) acc[a][b] = (f32x4){0.f, 0.f, 0.f, 0.f};

    for (int kt = 0; kt < HD2 / 64; kt++) {
        __syncthreads();
#pragma unroll
        for (int j = 0; j < 4; j++) {
            GLD16(srcA[j] + kt * 64, &As[(w * 256 + j * 64) * 8]);
            GLD16(srcB[j] + kt * 64, &Bs[(w * 256 + j * 64) * 8]);
        }
        __syncthreads();
#pragma unroll
        for (int s = 0; s < 2; s++) {
            bf16x8 af[4], bfr[4];
            int q = lane >> 4, cA = s * 4 + q;
#pragma unroll
            for (int i = 0; i < 4; i++) {
                int rowA = wm + i * 16 + (lane & 15);
                af[i] = *(const bf16x8*)&As[(rowA * 8 + (cA ^ (rowA & 7))) * 8];
                int rowB = wn + i * 16 + (lane & 15);
                bfr[i] = *(const bf16x8*)&Bs[(rowB * 8 + (cA ^ (rowB & 7))) * 8];
            }
#pragma unroll
            for (int im = 0; im < 4; im++)
#pragma unroll
                for (int in = 0; in < 4; in++)
                    acc[im][in] = __builtin_amdgcn_mfma_f32_16x16x32_bf16(
                        af[im], bfr[in], acc[im][in], 0, 0, 0);
        }
    }

    // epilogue: hoist the 16 per-row (tok, wgt) pairs out of the in-loop
    int q = lane >> 4;
    int toks[16]; float wgts[16];
#pragma unroll
    for (int im = 0; im < 4; im++)
#pragma unroll
        for (int i = 0; i < 4; i++) {
            int r = r0 + wm + im * 16 + q * 4 + i;
            int rc = r < ROWS - 1 ? r : ROWS - 1;
            toks[im * 4 + i] = rows_tok[rc];
            wgts[im * 4 + i] = rows_w[rc];
        }
    const float* b2e = b2 + (size_t)e * HD + n0 + wn;
#pragma unroll
    for (int in = 0; in < 4; in++) {
        float bias = b2e[in * 16 + (lane & 15)];
#pragma unroll
        for (int im = 0; im < 4; im++) {
#pragma unroll
            for (int i = 0; i < 4; i++) {
                int r = r0 + wm + im * 16 + q * 4 + i;
                if (r < rend) {
                    float v = (acc[im][in][i] + bias) * wgts[im * 4 + i];
                    atomicAdd(&out[(size_t)toks[im * 4 + i] * HD + n0 + wn + in * 16 + (lane & 15)], v);
                }
            }
        }
    }
}

extern "C" void kernel_launch(void* const* d_in, const int* in_sizes, int n_in,
                              void* d_out, int out_size, void* d_ws, size_t ws_size,
                              hipStream_t stream) {
    const float* x  = (const float*)d_in[0];
    const float* gw = (const float*)d_in[1];
    const float* w1 = (const float*)d_in[2];
    const float* b1 = (const float*)d_in[3];
    const float* w2 = (const float*)d_in[4];
    const float* b2 = (const float*)d_in[5];
    float* out = (float*)d_out;

    uint8_t* ws = (uint8_t*)d_ws;
    unsigned short* Xbf = (unsigned short*)(ws);                  // 32 MiB
    unsigned short* W1T = (unsigned short*)(ws + 33554432ull);    // 32 MiB
    unsigned short* W2T = (unsigned short*)(ws + 67108864ull);    // 32 MiB
    unsigned short* HDN = (unsigned short*)(ws + 100663296ull);   // 128 MiB
    int*   meta     = (int*)(ws + 234881024ull);
    int*   tok_e    = meta + 2048;
    int*   tok_slot = tok_e + ROWS;
    float* tok_w    = (float*)(tok_slot + ROWS);
    int*   rows_tok = (int*)(tok_w + ROWS);
    float* rows_w   = (float*)(rows_tok + ROWS);

    hipMemsetAsync(meta, 0, 1024, stream);   // zero padded counters
    hipMemsetAsync(d_out, 0, (size_t)out_size * sizeof(float), stream);

    cvt_wT<<<dim3(HD2 / 32, HD / 32, NE), 256, 0, stream>>>(w1, W1T, HD, HD2);
    cvt_wT<<<dim3(HD / 32, HD2 / 32, NE), 256, 0, stream>>>(w2, W2T, HD2, HD);
    router_k<<<T_TOK / RTOK, 256, 0, stream>>>(x, gw, meta, tok_e, tok_slot, tok_w, Xbf);
    offsets_k<<<1, 64, 0, stream>>>(meta);
    scatter_k<<<ROWS / 256, 256, 0, stream>>>(meta, tok_e, tok_slot, tok_w, rows_tok, rows_w);
    gemm1_k<<<dim3(HD2 / 128, MAXT), 256, 0, stream>>>(Xbf, W1T, b1, meta, rows_tok, HDN);
    gemm2_k<<<dim3(HD / 128, MAXT), 256, 0, stream>>>(HDN, W2T, b2, meta, rows_tok, rows_w, out);
}

// Round 4
// 772.901 us; speedup vs baseline: 1.1846x; 1.1846x over previous
//
#include <hip/hip_runtime.h>
#include <hip/hip_bf16.h>
#include <stdint.h>

#define T_TOK 16384
#define HD    1024
#define HD2   2048
#define NE    8
#define ROWS  (2*T_TOK)   // 32768 expert-row assignments (exactly 2 per token)
#define MAXT  264         // max M-tiles: 32768/128 + 8
#define RTOK  32          // tokens per router block

// meta layout (ints): cnt[e] at meta[e*32] (padded to cache lines, e<8)
//   nt at meta[256]; offs[8] at meta+272; tile_e/tile_r0/tile_re at meta+288 (+MAXT,+2*MAXT)
#define M_NT    256
#define M_OFFS  272
#define M_TILES 288

typedef __bf16 bf16x8 __attribute__((ext_vector_type(8)));
typedef float f32x4 __attribute__((ext_vector_type(4)));
typedef float f32x16 __attribute__((ext_vector_type(16)));

// async 16B global->LDS (dest = wave-uniform base + lane*16)
#define GLD16(g, l) __builtin_amdgcn_global_load_lds( \
    (const __attribute__((address_space(1))) void*)(g), \
    (__attribute__((address_space(3))) void*)(l), 16, 0, 0)

__device__ inline unsigned short f2bf(float f) {  // RNE fp32->bf16
    unsigned int u = __float_as_uint(f);
    unsigned int r = (u + 0x7fffu + ((u >> 16) & 1u)) >> 16;
    return (unsigned short)r;
}

// ------------- fp32 [E][K][N] -> bf16 [E][N][K] transpose-convert -------------
__global__ __launch_bounds__(256) void cvt_wT(const float* __restrict__ w,
                                              unsigned short* __restrict__ wt,
                                              int K, int N) {
    __shared__ float t[32][33];
    int e = blockIdx.z;
    int n0 = blockIdx.x * 32, k0 = blockIdx.y * 32;
    int r = threadIdx.x >> 3;          // 0..31
    int c4 = (threadIdx.x & 7) * 4;    // 0..28
    const float* src = w + ((size_t)e * K + k0 + r) * N + n0 + c4;
    float4 v = *(const float4*)src;
    t[r][c4] = v.x; t[r][c4+1] = v.y; t[r][c4+2] = v.z; t[r][c4+3] = v.w;
    __syncthreads();
    int cc = threadIdx.x & 7;
    ushort4 o;
    o.x = f2bf(t[cc*4+0][r]); o.y = f2bf(t[cc*4+1][r]);
    o.z = f2bf(t[cc*4+2][r]); o.w = f2bf(t[cc*4+3][r]);
    *(ushort4*)(wt + ((size_t)e * N + n0 + r) * K + k0 + cc*4) = o;
}

// ------- router: fp32 logits, top-2, block-aggregated counting, fused x->bf16 -------
__global__ __launch_bounds__(256) void router_k(const float* __restrict__ x,
        const float* __restrict__ gw, int* __restrict__ meta,
        int* __restrict__ tok_e, int* __restrict__ tok_slot, float* __restrict__ tok_w,
        unsigned short* __restrict__ xb) {
    __shared__ float g[NE * HD];                 // transposed [e][k], 32 KB
    __shared__ int   le[RTOK * 2];
    __shared__ float lw[RTOK * 2];
    __shared__ int   lslot[RTOK * 2];
    __shared__ int   lcnt[NE];
    __shared__ int   lbase[NE];
    for (int i = threadIdx.x; i < NE * HD; i += 256) {
        int k = i >> 3, e = i & 7;
        g[e * HD + k] = gw[i];
    }
    if (threadIdx.x < NE) lcnt[threadIdx.x] = 0;
    __syncthreads();

    int wave = threadIdx.x >> 6, lane = threadIdx.x & 63;
    int t0 = blockIdx.x * RTOK;
    for (int i = 0; i < RTOK / 4; i++) {         // each wave: 8 tokens
        int tt = wave * (RTOK / 4) + i;
        int t = t0 + tt;
        const float4* xr = (const float4*)(x + (size_t)t * HD);
        float acc[NE];
#pragma unroll
        for (int e = 0; e < NE; e++) acc[e] = 0.f;
#pragma unroll
        for (int j = 0; j < HD / 256; j++) {     // 4 iters of float4
            float4 xv = xr[lane + 64 * j];
            ushort4 o4;
            o4.x = f2bf(xv.x); o4.y = f2bf(xv.y);
            o4.z = f2bf(xv.z); o4.w = f2bf(xv.w);
            *(ushort4*)(xb + (size_t)t * HD + (lane + 64 * j) * 4) = o4;
#pragma unroll
            for (int e = 0; e < NE; e++) {
                float4 gv = *(const float4*)&g[e * HD + (lane + 64 * j) * 4];
                acc[e] += xv.x * gv.x + xv.y * gv.y + xv.z * gv.z + xv.w * gv.w;
            }
        }
#pragma unroll
        for (int e = 0; e < NE; e++) {
            float v = acc[e];
#pragma unroll
            for (int off = 32; off > 0; off >>= 1) v += __shfl_down(v, off, 64);
            acc[e] = v;
        }
        if (lane == 0) {
            int e1 = 0; float l1 = acc[0];
#pragma unroll
            for (int e = 1; e < NE; e++) if (acc[e] > l1) { l1 = acc[e]; e1 = e; }
            int e2 = -1; float l2 = -3.0e38f;
#pragma unroll
            for (int e = 0; e < NE; e++) if (e != e1 && acc[e] > l2) { l2 = acc[e]; e2 = e; }
            float w1 = 1.f / (1.f + expf(l2 - l1));   // softmax denom cancels in top-2 renorm
            le[tt * 2] = e1;     le[tt * 2 + 1] = e2;
            lw[tt * 2] = w1;     lw[tt * 2 + 1] = 1.f - w1;
        }
    }
    __syncthreads();
    // block-local slot assignment (LDS atomics, 8 addresses)
    if (threadIdx.x < RTOK * 2)
        lslot[threadIdx.x] = atomicAdd(&lcnt[le[threadIdx.x]], 1);
    __syncthreads();
    // one global atomic per expert per block, counters padded to cache lines
    if (threadIdx.x < NE)
        lbase[threadIdx.x] = atomicAdd(&meta[threadIdx.x * 32], lcnt[threadIdx.x]);
    __syncthreads();
    if (threadIdx.x < RTOK * 2) {
        int gi = t0 * 2 + threadIdx.x;           // global row index = token*2 + k
        int e = le[threadIdx.x];
        tok_e[gi]    = e;
        tok_slot[gi] = lbase[e] + lslot[threadIdx.x];
        tok_w[gi]    = lw[threadIdx.x];
    }
}

// ------------- offsets + M-tile table (one wave, parallel fill) -------------
__global__ __launch_bounds__(64) void offsets_k(int* __restrict__ meta) {
    int lane = threadIdx.x;
    int cl = (lane < NE) ? meta[lane * 32] : 0;
    int cnt[NE], offs[NE], tbase[NE];
    int o = 0, tb = 0;
#pragma unroll
    for (int e = 0; e < NE; e++) {
        cnt[e] = __shfl(cl, e, 64);
        offs[e] = o;  o += cnt[e];
        tbase[e] = tb; tb += (cnt[e] + 127) >> 7;
    }
    int nt = tb;
    if (lane == 0) meta[M_NT] = nt;
    if (lane < NE) meta[M_OFFS + lane] = offs[lane];
    for (int i = lane; i < nt; i += 64) {
        int e = 0;
#pragma unroll
        for (int k = 1; k < NE; k++) if (i >= tbase[k]) e = k;
        int m = i - tbase[e];
        int r0 = offs[e] + m * 128;
        int re = offs[e] + cnt[e];
        if (r0 + 128 < re) re = r0 + 128;
        meta[M_TILES + i] = e;
        meta[M_TILES + MAXT + i] = r0;
        meta[M_TILES + 2 * MAXT + i] = re;
    }
}

// ------------- scatter token ids/weights into compact row space -------------
__global__ __launch_bounds__(256) void scatter_k(const int* __restrict__ meta,
        const int* __restrict__ tok_e, const int* __restrict__ tok_slot,
        const float* __restrict__ tok_w, int* __restrict__ rows_tok,
        float* __restrict__ rows_w) {
    int i = blockIdx.x * 256 + threadIdx.x;     // 0..ROWS-1
    const int* offs = meta + M_OFFS;
    int e = tok_e[i];
    int r = offs[e] + tok_slot[i];
    rows_tok[r] = i >> 1;
    rows_w[r] = tok_w[i];
}

// ---------------- GEMM1: hdn = relu(gather(X) @ W1 + b1), bf16 out ----------------
// (R2 form: 16x16x32 MFMA, natural block mapping)
__global__ __launch_bounds__(256) void gemm1_k(
    const unsigned short* __restrict__ Xbf,   // [T][HD]
    const unsigned short* __restrict__ W1T,   // [E][HD2][HD] (n-major, k-contig)
    const float* __restrict__ b1,             // [E][HD2]
    const int* __restrict__ meta,
    const int* __restrict__ rows_tok,
    unsigned short* __restrict__ hdn)         // [ROWS][HD2]
{
    __shared__ unsigned short As[128 * 64];
    __shared__ unsigned short Bs[128 * 64];
    int nt = meta[M_NT];
    int mt = blockIdx.y;
    if (mt >= nt) return;
    int e    = meta[M_TILES + mt];
    int r0   = meta[M_TILES + MAXT + mt];
    int rend = meta[M_TILES + 2 * MAXT + mt];
    int n0 = blockIdx.x * 128;

    int tid = threadIdx.x, w = tid >> 6, lane = tid & 63;

    // staging: granule g = w*256 + j*64 + lane holds tile(row=g>>3, c=(g&7)^(row&7))
    const unsigned short* srcA[4];
    const unsigned short* srcB[4];
#pragma unroll
    for (int j = 0; j < 4; j++) {
        int g = w * 256 + j * 64 + lane;
        int row = g >> 3;
        int c = (g & 7) ^ (row & 7);
        int grow = r0 + row; grow = grow < ROWS - 1 ? grow : ROWS - 1;
        int tok = rows_tok[grow];
        srcA[j] = Xbf + (size_t)tok * HD + c * 8;
        srcB[j] = W1T + ((size_t)e * HD2 + n0 + row) * HD + c * 8;
    }
    int wm = (w & 1) * 64, wn = (w >> 1) * 64;

    f32x4 acc[4][4];
#pragma unroll
    for (int a = 0; a < 4; a++)
#pragma unroll
        for (int b = 0; b < 4; b++) acc[a][b] = (f32x4){0.f, 0.f, 0.f, 0.f};

    for (int kt = 0; kt < HD / 64; kt++) {
        __syncthreads();
#pragma unroll
        for (int j = 0; j < 4; j++) {
            GLD16(srcA[j] + kt * 64, &As[(w * 256 + j * 64) * 8]);
            GLD16(srcB[j] + kt * 64, &Bs[(w * 256 + j * 64) * 8]);
        }
        __syncthreads();
#pragma unroll
        for (int s = 0; s < 2; s++) {
            bf16x8 af[4], bfr[4];
            int q = lane >> 4, cA = s * 4 + q;
#pragma unroll
            for (int i = 0; i < 4; i++) {
                int rowA = wm + i * 16 + (lane & 15);
                af[i] = *(const bf16x8*)&As[(rowA * 8 + (cA ^ (rowA & 7))) * 8];
                int rowB = wn + i * 16 + (lane & 15);
                bfr[i] = *(const bf16x8*)&Bs[(rowB * 8 + (cA ^ (rowB & 7))) * 8];
            }
#pragma unroll
            for (int im = 0; im < 4; im++)
#pragma unroll
                for (int in = 0; in < 4; in++)
                    acc[im][in] = __builtin_amdgcn_mfma_f32_16x16x32_bf16(
                        af[im], bfr[in], acc[im][in], 0, 0, 0);
        }
    }

    const float* b1e = b1 + (size_t)e * HD2 + n0 + wn;
    int q = lane >> 4;
#pragma unroll
    for (int in = 0; in < 4; in++) {
        float bias = b1e[in * 16 + (lane & 15)];
#pragma unroll
        for (int im = 0; im < 4; im++) {
            int rbase = r0 + wm + im * 16 + q * 4;
#pragma unroll
            for (int i = 0; i < 4; i++) {
                int r = rbase + i;
                if (r < rend) {
                    float v = acc[im][in][i] + bias;
                    v = v > 0.f ? v : 0.f;
                    hdn[(size_t)r * HD2 + n0 + wn + in * 16 + (lane & 15)] = f2bf(v);
                }
            }
        }
    }
}

// ---------------- GEMM2: out[tok] += w * (hdn @ W2 + b2), fp32 atomics ----------------
// Experiment R4: 32x32x16 MFMA (half the MFMA issue count, same LDS read count)
__global__ __launch_bounds__(256) void gemm2_k(
    const unsigned short* __restrict__ hdn,   // [ROWS][HD2]
    const unsigned short* __restrict__ W2T,   // [E][HD][HD2]
    const float* __restrict__ b2,             // [E][HD]
    const int* __restrict__ meta,
    const int* __restrict__ rows_tok,
    const float* __restrict__ rows_w,
    float* __restrict__ out)                  // [T][HD]
{
    __shared__ unsigned short As[128 * 64];
    __shared__ unsigned short Bs[128 * 64];
    int nt = meta[M_NT];
    int mt = blockIdx.y;
    if (mt >= nt) return;
    int e    = meta[M_TILES + mt];
    int r0   = meta[M_TILES + MAXT + mt];
    int rend = meta[M_TILES + 2 * MAXT + mt];
    int n0 = blockIdx.x * 128;

    int tid = threadIdx.x, w = tid >> 6, lane = tid & 63;

    const unsigned short* srcA[4];
    const unsigned short* srcB[4];
#pragma unroll
    for (int j = 0; j < 4; j++) {
        int g = w * 256 + j * 64 + lane;
        int row = g >> 3;
        int c = (g & 7) ^ (row & 7);
        int grow = r0 + row; grow = grow < ROWS - 1 ? grow : ROWS - 1;
        srcA[j] = hdn + (size_t)grow * HD2 + c * 8;
        srcB[j] = W2T + ((size_t)e * HD + n0 + row) * HD2 + c * 8;
    }
    int wm = (w & 1) * 64, wn = (w >> 1) * 64;

    f32x16 acc[2][2];
#pragma unroll
    for (int a = 0; a < 2; a++)
#pragma unroll
        for (int b = 0; b < 2; b++)
#pragma unroll
            for (int i = 0; i < 16; i++) acc[a][b][i] = 0.f;

    int kh = lane >> 5;          // k-half selector (0/1)
    int rl = lane & 31;          // row within 32
    for (int kt = 0; kt < HD2 / 64; kt++) {
        __syncthreads();
#pragma unroll
        for (int j = 0; j < 4; j++) {
            GLD16(srcA[j] + kt * 64, &As[(w * 256 + j * 64) * 8]);
            GLD16(srcB[j] + kt * 64, &Bs[(w * 256 + j * 64) * 8]);
        }
        __syncthreads();
#pragma unroll
        for (int s = 0; s < 4; s++) {            // 4 x K=16 steps
            int c = s * 2 + kh;                  // granule col 0..7
            bf16x8 af[2], bfr[2];
#pragma unroll
            for (int i = 0; i < 2; i++) {
                int rowA = wm + i * 32 + rl;
                af[i] = *(const bf16x8*)&As[(rowA * 8 + (c ^ (rowA & 7))) * 8];
                int rowB = wn + i * 32 + rl;
                bfr[i] = *(const bf16x8*)&Bs[(rowB * 8 + (c ^ (rowB & 7))) * 8];
            }
#pragma unroll
            for (int im = 0; im < 2; im++)
#pragma unroll
                for (int in = 0; in < 2; in++)
                    acc[im][in] = __builtin_amdgcn_mfma_f32_32x32x16_bf16(
                        af[im], bfr[in], acc[im][in], 0, 0, 0);
        }
    }

    // epilogue: C/D layout col=lane&31, row=(reg&3)+8*(reg>>2)+4*(lane>>5)
    int col = lane & 31;
    float bias0 = b2[(size_t)e * HD + n0 + wn + col];
    float bias1 = b2[(size_t)e * HD + n0 + wn + 32 + col];
#pragma unroll
    for (int im = 0; im < 2; im++) {
        int rb = r0 + wm + im * 32 + 4 * kh;
#pragma unroll
        for (int g = 0; g < 4; g++) {            // reg>>2
            int toks[4]; float wgts[4];
#pragma unroll
            for (int t = 0; t < 4; t++) {        // reg&3
                int r = rb + 8 * g + t;
                int rc = r < ROWS - 1 ? r : ROWS - 1;
                toks[t] = rows_tok[rc];
                wgts[t] = rows_w[rc];
            }
#pragma unroll
            for (int in = 0; in < 2; in++) {
                float bias = in ? bias1 : bias0;
#pragma unroll
                for (int t = 0; t < 4; t++) {
                    int r = rb + 8 * g + t;
                    if (r < rend) {
                        float v = (acc[im][in][g * 4 + t] + bias) * wgts[t];
                        atomicAdd(&out[(size_t)toks[t] * HD + n0 + wn + in * 32 + col], v);
                    }
                }
            }
        }
    }
}

extern "C" void kernel_launch(void* const* d_in, const int* in_sizes, int n_in,
                              void* d_out, int out_size, void* d_ws, size_t ws_size,
                              hipStream_t stream) {
    const float* x  = (const float*)d_in[0];
    const float* gw = (const float*)d_in[1];
    const float* w1 = (const float*)d_in[2];
    const float* b1 = (const float*)d_in[3];
    const float* w2 = (const float*)d_in[4];
    const float* b2 = (const float*)d_in[5];
    float* out = (float*)d_out;

    uint8_t* ws = (uint8_t*)d_ws;
    unsigned short* Xbf = (unsigned short*)(ws);                  // 32 MiB
    unsigned short* W1T = (unsigned short*)(ws + 33554432ull);    // 32 MiB
    unsigned short* W2T = (unsigned short*)(ws + 67108864ull);    // 32 MiB
    unsigned short* HDN = (unsigned short*)(ws + 100663296ull);   // 128 MiB
    int*   meta     = (int*)(ws + 234881024ull);
    int*   tok_e    = meta + 2048;
    int*   tok_slot = tok_e + ROWS;
    float* tok_w    = (float*)(tok_slot + ROWS);
    int*   rows_tok = (int*)(tok_w + ROWS);
    float* rows_w   = (float*)(rows_tok + ROWS);

    hipMemsetAsync(meta, 0, 1024, stream);   // zero padded counters
    hipMemsetAsync(d_out, 0, (size_t)out_size * sizeof(float), stream);

    cvt_wT<<<dim3(HD2 / 32, HD / 32, NE), 256, 0, stream>>>(w1, W1T, HD, HD2);
    cvt_wT<<<dim3(HD / 32, HD2 / 32, NE), 256, 0, stream>>>(w2, W2T, HD2, HD);
    router_k<<<T_TOK / RTOK, 256, 0, stream>>>(x, gw, meta, tok_e, tok_slot, tok_w, Xbf);
    offsets_k<<<1, 64, 0, stream>>>(meta);
    scatter_k<<<ROWS / 256, 256, 0, stream>>>(meta, tok_e, tok_slot, tok_w, rows_tok, rows_w);
    gemm1_k<<<dim3(HD2 / 128, MAXT), 256, 0, stream>>>(Xbf, W1T, b1, meta, rows_tok, HDN);
    gemm2_k<<<dim3(HD / 128, MAXT), 256, 0, stream>>>(HDN, W2T, b2, meta, rows_tok, rows_w, out);
}